// Round 2
// baseline (5104.308 us; speedup 1.0000x reference)
//
#include <hip/hip_runtime.h>

// ---------------------------------------------------------------------------
// RNN scan on MI355X — round 4.
// Model from rounds 2/3: the LDS data-return bus (≈12 cyc per ds_read_b128
// per CU) was the wall: 32 b128/wave/step ≈ 3100 cyc vs 1024 cyc VALU floor.
// R4 cuts LDS to ~9 insts/wave/step:
//   - U tail (24 uint4-slots/thread) streamed from GLOBAL (L2 ≈225 B/cyc/CU
//     with 8 active CUs/XCD) on the vmem pipe, 3-deep software pipeline.
//   - k-split s=8 inside each wave: lane o=l&7 owns pairs [32o,32o+32),
//     8 cols; h-reads drop to 8 b128/thread; reduction is a 7-op butterfly
//     with DPP quad_perm for xor1/xor2 (VALU pipe) + ds_swizzle for xor4.
//   - h chunks at stride 144 B so the wave's 8 broadcast reads tile all 32
//     banks conflict-free; double-buffered, ONE barrier/step.
// ---------------------------------------------------------------------------

#define NRP 40            // uint4 slots resident in VGPRs (pairs 0..19, 2 quads)
#define NTG 24            // uint4 slots streamed from global (pairs 20..31)

typedef _Float16 h2_t __attribute__((ext_vector_type(2)));
union U32H2 { unsigned u; h2_t h; _Float16 f[2]; };

__device__ inline unsigned pkf16(float a, float b){
  U32H2 v; v.f[0] = (_Float16)a; v.f[1] = (_Float16)b; return v.u;
}

__device__ inline float dot2(unsigned a, unsigned b, float c){
  U32H2 x, y; x.u = a; y.u = b;
#if __has_builtin(__builtin_amdgcn_fdot2)
  return __builtin_amdgcn_fdot2(x.h, y.h, c, false);   // v_dot2_f32_f16
#else
  return c + (float)x.f[0]*(float)y.f[0] + (float)x.f[1]*(float)y.f[1];
#endif
}

// cross-lane: xor1/xor2 via DPP quad_perm (VALU pipe), xor4 via ds_swizzle
__device__ inline float sxor1(float v){
#if __has_builtin(__builtin_amdgcn_mov_dpp)
  return __int_as_float(__builtin_amdgcn_mov_dpp(__float_as_int(v), 0xB1, 0xF, 0xF, true)); // [1,0,3,2]
#else
  return __shfl_xor(v, 1);
#endif
}
__device__ inline float sxor2(float v){
#if __has_builtin(__builtin_amdgcn_mov_dpp)
  return __int_as_float(__builtin_amdgcn_mov_dpp(__float_as_int(v), 0x4E, 0xF, 0xF, true)); // [2,3,0,1]
#else
  return __shfl_xor(v, 2);
#endif
}
__device__ inline float sxor4(float v){
#if __has_builtin(__builtin_amdgcn_ds_swizzle)
  return __int_as_float(__builtin_amdgcn_ds_swizzle(__float_as_int(v), 0x101F)); // xor 4
#else
  return __shfl_xor(v, 4);
#endif
}

// ---------------------------------------------------------------------------
// P: pack weights. 256 blocks x 256 threads.
//  - Wp[kp*512+j] = pack(Ww[2kp][j], Ww[2kp+1][j])        (idx < 65536)
//  - U layout for scan thread t (w=t>>6, g=(t>>3)&7, o=t&7), slot j<64:
//      j -> (pp, q): j<40: pp=j>>1, q=j&1 -> UrP[j*512+t]
//                    j>=40: j2=j-40, pp=20+(j2>>1), q=j2&1 -> UtG[j2*512+t]
//      pair p = 32o + pp, k0 = 2p
//      cols c_e = 64w + g*8 + 4q + e (e=0..3)
//      v = { pack(U[k0][c_e], U[k0+1][c_e]) }
// ---------------------------------------------------------------------------
__global__ __launch_bounds__(256) void prep_pack(const float* __restrict__ Ww,
                                                 const float* __restrict__ Uw,
                                                 unsigned* __restrict__ Wp,
                                                 uint4* __restrict__ UrP,
                                                 uint4* __restrict__ UtG){
  int idx = blockIdx.x*256 + threadIdx.x;
  { // W pack
    int kp = idx >> 9, j = idx & 511;
    Wp[idx] = pkf16(Ww[(2*kp)*512 + j], Ww[(2*kp+1)*512 + j]);
  }
  if (idx < 512*64){
    int t = idx & 511, j = idx >> 9;          // j = uint4 slot 0..63
    int w = t >> 6, g = (t >> 3) & 7, o = t & 7;
    int pp, q;
    if (j < NRP){ pp = j >> 1;            q = j & 1; }
    else        { int j2 = j - NRP; pp = 20 + (j2 >> 1); q = j2 & 1; }
    int p = 32*o + pp, k0 = 2*p;
    uint4 v;
    unsigned* vv = (unsigned*)&v;
    #pragma unroll
    for (int e=0;e<4;e++){
      int c = 64*w + g*8 + 4*q + e;
      vv[e] = pkf16(Uw[k0*512 + c], Uw[(k0+1)*512 + c]);
    }
    if (j < NRP) UrP[j*512 + t] = v;
    else         UtG[(j-NRP)*512 + t] = v;
  }
}

// ---------------------------------------------------------------------------
// G: wx GEMM. Output f16: wxh[(b*2048+s)*512 + col].
// ---------------------------------------------------------------------------
__global__ __launch_bounds__(256) void gemm_wx(const float* __restrict__ x,
                                               const unsigned* __restrict__ Wp,
                                               const float* __restrict__ Wb,
                                               _Float16* __restrict__ wxh){
  __shared__ unsigned xt[32][128];      // 16 KB
  const int tid = threadIdx.x;
  const int b = blockIdx.x >> 6, sb = blockIdx.x & 63;
  const float* xrow = x + ((size_t)(b*2048 + sb*32))*256;
  #pragma unroll
  for (int i=0;i<8;i++){
    int f = i*256 + tid;
    int r = f >> 6, c4 = f & 63;
    float4 v = ((const float4*)xrow)[r*64 + c4];
    xt[r][2*c4]   = pkf16(v.x, v.y);
    xt[r][2*c4+1] = pkf16(v.z, v.w);
  }
  float acc0[32], acc1[32];
  #pragma unroll
  for (int r=0;r<32;r++){ acc0[r]=0.f; acc1[r]=0.f; }
  __syncthreads();
  #pragma unroll 4
  for (int kp=0;kp<128;kp++){
    unsigned w0 = Wp[kp*512 + tid];
    unsigned w1 = Wp[kp*512 + tid + 256];
    #pragma unroll
    for (int r=0;r<32;r++){
      unsigned xv = xt[r][kp];
      acc0[r] = dot2(xv, w0, acc0[r]);
      acc1[r] = dot2(xv, w1, acc1[r]);
    }
  }
  float wb0 = Wb[tid], wb1 = Wb[tid+256];
  _Float16* o = wxh + ((size_t)(b*2048 + sb*32))*512;
  #pragma unroll
  for (int r=0;r<32;r++){
    o[r*512 + tid]       = (_Float16)(acc0[r]+wb0);
    o[r*512 + 256 + tid] = (_Float16)(acc1[r]+wb1);
  }
}

// ---------------------------------------------------------------------------
// R: sequential scan. 64 blocks x 512 threads, __launch_bounds__(512,2).
// Thread t: w=t>>6 (wave, owns cols [64w,64w+64)), g=(t>>3)&7, o=t&7.
//   Computes cols 64w+g*8+{0..7} over pairs [32o,32o+32): 8 acc x 32 pairs
//   = 256 dot2. Butterfly over o leaves lane with col 64w+g*8+bitrev3(o).
// LDS: h double buffer 2x1152 B (8 chunks x 144 B: elems [64o,64o+64) at
//   o*144; stride 144 => the 8 broadcast b128 reads tile all 32 banks).
// ---------------------------------------------------------------------------
__global__ __launch_bounds__(512, 2) void rnn_scan(const uint4* __restrict__ UrP,
                                                   const uint4* __restrict__ UtG,
                                                   const _Float16* __restrict__ wxh,
                                                   const float* __restrict__ Ub,
                                                   const float* __restrict__ Vw,
                                                   const float* __restrict__ Vb,
                                                   float* __restrict__ out){
  __shared__ __align__(16) char hb[2*1152];      // h double buffer
  __shared__ float rbuf[16];
  const int t = threadIdx.x;
  const int b = blockIdx.x;
  const int w = t >> 6, g = (t >> 3) & 7, o = t & 7;
  const bool bo1 = (o & 1), bo2 = (o & 2), bo4 = (o & 4);
  const int jfin = ((o & 1) << 2) | (o & 2) | ((o & 4) >> 2);  // bitrev3(o)
  const int colf = 64*w + g*8 + jfin;            // this thread's final column

  uint4 ureg[NRP];                               // 160 regs: pairs 0..19
  #pragma unroll
  for (int j=0;j<NRP;j++) ureg[j] = UrP[j*512 + t];
  for (int i=t;i<576;i+=512) ((unsigned*)hb)[i] = 0;   // zero both h buffers
  const float ub_c = Ub[colf];
  const _Float16* wxb = wxh + (size_t)b*2048*512;
  _Float16 wc = wxb[colf];                       // wx[ts=0]
  _Float16 wn = wxb[512 + colf];                 // wx[ts=1]
  const uint4* hq0 = (const uint4*)(hb +        o*144);  // read even ts
  const uint4* hq1 = (const uint4*)(hb + 1152 + o*144);  // read odd ts
  _Float16* hw1 = (_Float16*)(hb + 1152 + w*144) + (colf & 63);  // write even ts
  _Float16* hw0 = (_Float16*)(hb +        w*144) + (colf & 63);  // write odd ts
  const uint4* gb = UtG + t;                     // global U tail base
  float hf = 0.f;
  __syncthreads();

#define DOT8(ua, ub2, h2) { unsigned _h = (h2); \
    a0 = dot2((ua).x, _h, a0); a1 = dot2((ua).y, _h, a1); \
    a2 = dot2((ua).z, _h, a2); a3 = dot2((ua).w, _h, a3); \
    a4 = dot2((ub2).x, _h, a4); a5 = dot2((ub2).y, _h, a5); \
    a6 = dot2((ub2).z, _h, a6); a7 = dot2((ub2).w, _h, a7); }

#define STEP(HQ, HW, TS) { \
    /* issue global-tail batches 0..2 (pairs 20..25), 3-deep pipeline */ \
    uint4 x0=gb[0],    x1=gb[512],  x2=gb[1024], x3=gb[1536]; \
    uint4 y0=gb[2048], y1=gb[2560], y2=gb[3072], y3=gb[3584]; \
    uint4 z0=gb[4096], z1=gb[4608], z2=gb[5120], z3=gb[5632]; \
    _Float16 wuse = wc; wc = wn; \
    int tn = ((TS)+2 < 2048) ? ((TS)+2) : 2047; \
    wn = wxb[(size_t)tn*512 + colf]; \
    float a0=0.f,a1=0.f,a2=0.f,a3=0.f,a4=0.f,a5=0.f,a6=0.f,a7=0.f; \
    _Pragma("unroll") \
    for (int i=0;i<5;i++){                       /* reg pairs 0..19 */ \
      uint4 hv = (HQ)[i]; \
      DOT8(ureg[8*i+0], ureg[8*i+1], hv.x); \
      DOT8(ureg[8*i+2], ureg[8*i+3], hv.y); \
      DOT8(ureg[8*i+4], ureg[8*i+5], hv.z); \
      DOT8(ureg[8*i+6], ureg[8*i+7], hv.w); \
    } \
    uint4 hv5 = (HQ)[5], hv6 = (HQ)[6], hv7 = (HQ)[7]; \
    DOT8(x0, x1, hv5.x); DOT8(x2, x3, hv5.y);    /* pairs 20,21 */ \
    x0=gb[6144]; x1=gb[6656]; x2=gb[7168]; x3=gb[7680];      /* batch3 */ \
    DOT8(y0, y1, hv5.z); DOT8(y2, y3, hv5.w);    /* pairs 22,23 */ \
    y0=gb[8192]; y1=gb[8704]; y2=gb[9216]; y3=gb[9728];      /* batch4 */ \
    DOT8(z0, z1, hv6.x); DOT8(z2, z3, hv6.y);    /* pairs 24,25 */ \
    z0=gb[10240]; z1=gb[10752]; z2=gb[11264]; z3=gb[11776];  /* batch5 */ \
    DOT8(x0, x1, hv6.z); DOT8(x2, x3, hv6.w);    /* pairs 26,27 */ \
    DOT8(y0, y1, hv7.x); DOT8(y2, y3, hv7.y);    /* pairs 28,29 */ \
    DOT8(z0, z1, hv7.z); DOT8(z2, z3, hv7.w);    /* pairs 30,31 */ \
    /* butterfly over o (xor1,xor2 via DPP; xor4 via ds_swizzle) */ \
    float r0 = bo1 ? a0 : a4, r1 = bo1 ? a1 : a5; \
    float r2 = bo1 ? a2 : a6, r3 = bo1 ? a3 : a7; \
    r0 = sxor1(r0); r1 = sxor1(r1); r2 = sxor1(r2); r3 = sxor1(r3); \
    float q0 = (bo1 ? a4 : a0) + r0, q1 = (bo1 ? a5 : a1) + r1; \
    float q2 = (bo1 ? a6 : a2) + r2, q3 = (bo1 ? a7 : a3) + r3; \
    float s0 = bo2 ? q0 : q2, s1 = bo2 ? q1 : q3; \
    s0 = sxor2(s0); s1 = sxor2(s1); \
    float u0 = (bo2 ? q2 : q0) + s0, u1 = (bo2 ? q3 : q1) + s1; \
    float rv = bo4 ? u0 : u1; \
    rv = sxor4(rv); \
    float fin = (bo4 ? u1 : u0) + rv; \
    float pre = fin + (float)wuse + ub_c; \
    hf = 1.f - 2.f/(__expf(2.f*pre) + 1.f);      /* tanh */ \
    *(HW) = (_Float16)hf; \
    __syncthreads(); \
    asm volatile("" : "+v"(gb));                 /* keep U-tail loads in-loop */ \
  }

  #pragma unroll 1
  for (int it=0; it<1024; it++){
    STEP(hq0, hw1, 2*it);      // even step: read buf0, write buf1
    STEP(hq1, hw0, 2*it+1);    // odd  step: read buf1, write buf0
  }
#undef STEP
#undef DOT8

  // epilogue: out[b,:] = sigmoid(h_T @ V + Vb); thread t holds h_T[colf]
  float p0 = hf*Vw[2*colf], p1 = hf*Vw[2*colf+1];
  #pragma unroll
  for (int off=32; off>0; off>>=1){
    p0 += __shfl_down(p0, off);
    p1 += __shfl_down(p1, off);
  }
  if ((t & 63) == 0){
    rbuf[(t>>6)*2]   = p0;
    rbuf[(t>>6)*2+1] = p1;
  }
  __syncthreads();
  if (t == 0){
    float s0 = Vb[0], s1 = Vb[1];
    #pragma unroll
    for (int wv=0;wv<8;wv++){ s0 += rbuf[2*wv]; s1 += rbuf[2*wv+1]; }
    out[2*b]   = 1.f/(1.f + __expf(-s0));
    out[2*b+1] = 1.f/(1.f + __expf(-s1));
  }
}

// ---------------------------------------------------------------------------
extern "C" void kernel_launch(void* const* d_in, const int* in_sizes, int n_in,
                              void* d_out, int out_size, void* d_ws, size_t ws_size,
                              hipStream_t stream) {
  const float* x  = (const float*)d_in[0];   // [64,2048,256]
  const float* Ww = (const float*)d_in[1];   // [256,512]
  const float* Wb = (const float*)d_in[2];   // [512]
  const float* Uw = (const float*)d_in[3];   // [512,512]
  const float* Ub = (const float*)d_in[4];   // [512]
  const float* Vw = (const float*)d_in[5];   // [512,2]
  const float* Vb = (const float*)d_in[6];   // [2]
  float* out = (float*)d_out;                // [64,2]

  char* ws = (char*)d_ws;
  _Float16* wxh = (_Float16*)ws;                               // 134,217,728 B
  size_t off = 134217728;
  unsigned* Wp  = (unsigned*)(ws + off); off += 262144;
  uint4*    UrP = (uint4*)   (ws + off); off += (size_t)NRP*512*16;
  uint4*    UtG = (uint4*)   (ws + off);

  prep_pack<<<256, 256, 0, stream>>>(Ww, Uw, Wp, UrP, UtG);
  gemm_wx  <<<4096, 256, 0, stream>>>(x, Wp, Wb, wxh);
  rnn_scan <<<64, 512, 0, stream>>>(UrP, UtG, wxh, Ub, Vw, Vb, out);
}

// Round 3
// 3065.045 us; speedup vs baseline: 1.6653x; 1.6653x over previous
//
#include <hip/hip_runtime.h>

// ---------------------------------------------------------------------------
// RNN scan on MI355X — round 5.
// Confirmed model (R2/R3/R4 all fit): the scan is LDS-INSTRUCTION-throughput
// bound (~12 cyc per ds_read_b128 wave-inst per CU); the vmem/L2 path is
// ~35 B/cyc/CU (R4) — worse. VALU floor is only ~1150 cyc/step.
// R5 = R4's s=8 lane map (h-broadcast 128->32 wave-insts, verified correct)
// with the U-tail moved back to LDS and register residency maximized:
//   NRP=52 uint4 slots in regs (208 regs; AGPR-resident slots are read
//   directly by VOP3P on gfx950's unified file — R2 timing proved no move
//   tax), NTL=12 slots in LDS (96 KB).
// Per-CU LDS/step: 32 h + 96 tail + 8 swizzle + 8 write ~= 144 insts ~1620cy.
// ---------------------------------------------------------------------------

#define NRP 52            // uint4 slots resident in registers (pairs 0..25)
#define NTL 12            // uint4 slots resident in LDS       (pairs 26..31)

typedef _Float16 h2_t __attribute__((ext_vector_type(2)));
union U32H2 { unsigned u; h2_t h; _Float16 f[2]; };

__device__ inline unsigned pkf16(float a, float b){
  U32H2 v; v.f[0] = (_Float16)a; v.f[1] = (_Float16)b; return v.u;
}

__device__ inline float dot2(unsigned a, unsigned b, float c){
  U32H2 x, y; x.u = a; y.u = b;
#if __has_builtin(__builtin_amdgcn_fdot2)
  return __builtin_amdgcn_fdot2(x.h, y.h, c, false);   // v_dot2_f32_f16
#else
  return c + (float)x.f[0]*(float)y.f[0] + (float)x.f[1]*(float)y.f[1];
#endif
}

// cross-lane: xor1/xor2 via DPP quad_perm (VALU pipe), xor4 via ds_swizzle
__device__ inline float sxor1(float v){
#if __has_builtin(__builtin_amdgcn_mov_dpp)
  return __int_as_float(__builtin_amdgcn_mov_dpp(__float_as_int(v), 0xB1, 0xF, 0xF, true)); // [1,0,3,2]
#else
  return __shfl_xor(v, 1);
#endif
}
__device__ inline float sxor2(float v){
#if __has_builtin(__builtin_amdgcn_mov_dpp)
  return __int_as_float(__builtin_amdgcn_mov_dpp(__float_as_int(v), 0x4E, 0xF, 0xF, true)); // [2,3,0,1]
#else
  return __shfl_xor(v, 2);
#endif
}
__device__ inline float sxor4(float v){
#if __has_builtin(__builtin_amdgcn_ds_swizzle)
  return __int_as_float(__builtin_amdgcn_ds_swizzle(__float_as_int(v), 0x101F)); // xor 4
#else
  return __shfl_xor(v, 4);
#endif
}

// ---------------------------------------------------------------------------
// P: pack weights. 256 blocks x 256 threads.
//  - Wp[kp*512+j] = pack(Ww[2kp][j], Ww[2kp+1][j])        (idx < 65536)
//  - U layout for scan thread t (w=t>>6, g=(t>>3)&7, o=t&7), slot j<64:
//      j<NRP:  pp=j>>1, q=j&1            -> UrP[j*512+t]     (pairs 0..25)
//      j>=NRP: j2=j-NRP, pp=26+(j2>>1), q=j2&1 -> UtL[j2*512+t] (pairs 26..31)
//      pair p = 32o + pp, k0 = 2p
//      cols c_e = 64w + g*8 + 4q + e (e=0..3)
//      v = { pack(U[k0][c_e], U[k0+1][c_e]) }
// ---------------------------------------------------------------------------
__global__ __launch_bounds__(256) void prep_pack(const float* __restrict__ Ww,
                                                 const float* __restrict__ Uw,
                                                 unsigned* __restrict__ Wp,
                                                 uint4* __restrict__ UrP,
                                                 uint4* __restrict__ UtL){
  int idx = blockIdx.x*256 + threadIdx.x;
  { // W pack
    int kp = idx >> 9, j = idx & 511;
    Wp[idx] = pkf16(Ww[(2*kp)*512 + j], Ww[(2*kp+1)*512 + j]);
  }
  if (idx < 512*64){
    int t = idx & 511, j = idx >> 9;          // j = uint4 slot 0..63
    int w = t >> 6, g = (t >> 3) & 7, o = t & 7;
    int pp, q;
    if (j < NRP){ pp = j >> 1;            q = j & 1; }
    else        { int j2 = j - NRP; pp = 26 + (j2 >> 1); q = j2 & 1; }
    int p = 32*o + pp, k0 = 2*p;
    uint4 v;
    unsigned* vv = (unsigned*)&v;
    #pragma unroll
    for (int e=0;e<4;e++){
      int c = 64*w + g*8 + 4*q + e;
      vv[e] = pkf16(Uw[k0*512 + c], Uw[(k0+1)*512 + c]);
    }
    if (j < NRP) UrP[j*512 + t] = v;
    else         UtL[(j-NRP)*512 + t] = v;
  }
}

// ---------------------------------------------------------------------------
// G: wx GEMM. Output f16: wxh[(b*2048+s)*512 + col].
// ---------------------------------------------------------------------------
__global__ __launch_bounds__(256) void gemm_wx(const float* __restrict__ x,
                                               const unsigned* __restrict__ Wp,
                                               const float* __restrict__ Wb,
                                               _Float16* __restrict__ wxh){
  __shared__ unsigned xt[32][128];      // 16 KB
  const int tid = threadIdx.x;
  const int b = blockIdx.x >> 6, sb = blockIdx.x & 63;
  const float* xrow = x + ((size_t)(b*2048 + sb*32))*256;
  #pragma unroll
  for (int i=0;i<8;i++){
    int f = i*256 + tid;
    int r = f >> 6, c4 = f & 63;
    float4 v = ((const float4*)xrow)[r*64 + c4];
    xt[r][2*c4]   = pkf16(v.x, v.y);
    xt[r][2*c4+1] = pkf16(v.z, v.w);
  }
  float acc0[32], acc1[32];
  #pragma unroll
  for (int r=0;r<32;r++){ acc0[r]=0.f; acc1[r]=0.f; }
  __syncthreads();
  #pragma unroll 4
  for (int kp=0;kp<128;kp++){
    unsigned w0 = Wp[kp*512 + tid];
    unsigned w1 = Wp[kp*512 + tid + 256];
    #pragma unroll
    for (int r=0;r<32;r++){
      unsigned xv = xt[r][kp];
      acc0[r] = dot2(xv, w0, acc0[r]);
      acc1[r] = dot2(xv, w1, acc1[r]);
    }
  }
  float wb0 = Wb[tid], wb1 = Wb[tid+256];
  _Float16* o = wxh + ((size_t)(b*2048 + sb*32))*512;
  #pragma unroll
  for (int r=0;r<32;r++){
    o[r*512 + tid]       = (_Float16)(acc0[r]+wb0);
    o[r*512 + 256 + tid] = (_Float16)(acc1[r]+wb1);
  }
}

// ---------------------------------------------------------------------------
// R: sequential scan. 64 blocks x 512 threads, __launch_bounds__(512,2).
// Thread t: w=t>>6 (wave, owns cols [64w,64w+64)), g=(t>>3)&7, o=t&7.
//   Computes cols 64w+g*8+{0..7} over pairs [32o,32o+32): 8 acc x 32 pairs
//   = 256 dot2. Butterfly over o leaves lane with col 64w+g*8+bitrev3(o).
// LDS: utail 96 KB + h dbuf 2x1152 B (8 chunks x 144 B: elems [64o,64o+64)
//   at o*144; stride 144 => the 8 broadcast b128 reads tile all 32 banks).
// ---------------------------------------------------------------------------
__global__ __launch_bounds__(512, 2) void rnn_scan(const uint4* __restrict__ UrP,
                                                   const uint4* __restrict__ UtL,
                                                   const _Float16* __restrict__ wxh,
                                                   const float* __restrict__ Ub,
                                                   const float* __restrict__ Vw,
                                                   const float* __restrict__ Vb,
                                                   float* __restrict__ out){
  __shared__ uint4 utail[NTL*512];               // 96 KB
  __shared__ __align__(16) char hb[2*1152];      // h double buffer
  __shared__ float rbuf[16];
  const int t = threadIdx.x;
  const int b = blockIdx.x;
  const int w = t >> 6, g = (t >> 3) & 7, o = t & 7;
  const bool bo1 = (o & 1), bo2 = (o & 2), bo4 = (o & 4);
  const int jfin = ((o & 1) << 2) | (o & 2) | ((o & 4) >> 2);  // bitrev3(o)
  const int colf = 64*w + g*8 + jfin;            // this thread's final column

  uint4 ureg[NRP];                               // 208 regs (VGPR+AGPR unified)
  #pragma unroll
  for (int j=0;j<NRP;j++) ureg[j] = UrP[j*512 + t];
  #pragma unroll
  for (int i=0;i<NTL;i++) utail[i*512 + t] = UtL[i*512 + t];
  for (int i=t;i<576;i+=512) ((unsigned*)hb)[i] = 0;   // zero both h buffers
  const float ub_c = Ub[colf];
  const _Float16* wxb = wxh + (size_t)b*2048*512;
  _Float16 wc = wxb[colf];                       // wx[ts=0]
  _Float16 wn = wxb[512 + colf];                 // wx[ts=1]
  const uint4* hq0 = (const uint4*)(hb +        o*144);  // read even ts
  const uint4* hq1 = (const uint4*)(hb + 1152 + o*144);  // read odd ts
  _Float16* hw1 = (_Float16*)(hb + 1152 + w*144) + (colf & 63);  // write even ts
  _Float16* hw0 = (_Float16*)(hb +        w*144) + (colf & 63);  // write odd ts
  float hf = 0.f;
  __syncthreads();

#define DOT8(ua, ub2, h2) { unsigned _h = (h2); \
    a0 = dot2((ua).x, _h, a0); a1 = dot2((ua).y, _h, a1); \
    a2 = dot2((ua).z, _h, a2); a3 = dot2((ua).w, _h, a3); \
    a4 = dot2((ub2).x, _h, a4); a5 = dot2((ub2).y, _h, a5); \
    a6 = dot2((ub2).z, _h, a6); a7 = dot2((ub2).w, _h, a7); }

#define STEP(HQ, HW, TS) { \
    _Float16 wuse = wc; wc = wn; \
    int tn = ((TS)+2 < 2048) ? ((TS)+2) : 2047; \
    wn = wxb[(size_t)tn*512 + colf]; \
    float a0=0.f,a1=0.f,a2=0.f,a3=0.f,a4=0.f,a5=0.f,a6=0.f,a7=0.f; \
    /* tail group A issued early; consumed in h-group 6 */ \
    uint4 t0=utail[0*512+t], t1=utail[1*512+t], t2=utail[2*512+t], t3=utail[3*512+t]; \
    _Pragma("unroll") \
    for (int i=0;i<4;i++){                       /* reg pairs 0..15 */ \
      uint4 hv = (HQ)[i]; \
      DOT8(ureg[8*i+0], ureg[8*i+1], hv.x); \
      DOT8(ureg[8*i+2], ureg[8*i+3], hv.y); \
      DOT8(ureg[8*i+4], ureg[8*i+5], hv.z); \
      DOT8(ureg[8*i+6], ureg[8*i+7], hv.w); \
    } \
    /* tail group B issued; consumed in h-group 7 */ \
    uint4 t4=utail[4*512+t], t5=utail[5*512+t], t6=utail[6*512+t], t7=utail[7*512+t]; \
    _Pragma("unroll") \
    for (int i=4;i<6;i++){                       /* reg pairs 16..23 */ \
      uint4 hv = (HQ)[i]; \
      DOT8(ureg[8*i+0], ureg[8*i+1], hv.x); \
      DOT8(ureg[8*i+2], ureg[8*i+3], hv.y); \
      DOT8(ureg[8*i+4], ureg[8*i+5], hv.z); \
      DOT8(ureg[8*i+6], ureg[8*i+7], hv.w); \
    } \
    uint4 t8=utail[8*512+t], t9=utail[9*512+t], t10=utail[10*512+t], t11=utail[11*512+t]; \
    { uint4 hv = (HQ)[6];                        /* pairs 24,25 reg; 26,27 LDS */ \
      DOT8(ureg[48], ureg[49], hv.x); \
      DOT8(ureg[50], ureg[51], hv.y); \
      DOT8(t0, t1, hv.z); \
      DOT8(t2, t3, hv.w); } \
    { uint4 hv = (HQ)[7];                        /* pairs 28..31 LDS */ \
      DOT8(t4, t5, hv.x); \
      DOT8(t6, t7, hv.y); \
      DOT8(t8, t9, hv.z); \
      DOT8(t10, t11, hv.w); } \
    /* butterfly over o (xor1,xor2 via DPP; xor4 via ds_swizzle) */ \
    float r0 = bo1 ? a0 : a4, r1 = bo1 ? a1 : a5; \
    float r2 = bo1 ? a2 : a6, r3 = bo1 ? a3 : a7; \
    r0 = sxor1(r0); r1 = sxor1(r1); r2 = sxor1(r2); r3 = sxor1(r3); \
    float q0 = (bo1 ? a4 : a0) + r0, q1 = (bo1 ? a5 : a1) + r1; \
    float q2 = (bo1 ? a6 : a2) + r2, q3 = (bo1 ? a7 : a3) + r3; \
    float s0 = bo2 ? q0 : q2, s1 = bo2 ? q1 : q3; \
    s0 = sxor2(s0); s1 = sxor2(s1); \
    float u0 = (bo2 ? q2 : q0) + s0, u1 = (bo2 ? q3 : q1) + s1; \
    float rv = bo4 ? u0 : u1; \
    rv = sxor4(rv); \
    float fin = (bo4 ? u1 : u0) + rv; \
    float pre = fin + (float)wuse + ub_c; \
    hf = 1.f - 2.f/(__expf(2.f*pre) + 1.f);      /* tanh */ \
    *(HW) = (_Float16)hf; \
    __syncthreads();                             /* ONE barrier per step */ \
  }

  #pragma unroll 1
  for (int it=0; it<1024; it++){
    STEP(hq0, hw1, 2*it);      // even step: read buf0, write buf1
    STEP(hq1, hw0, 2*it+1);    // odd  step: read buf1, write buf0
  }
#undef STEP
#undef DOT8

  // epilogue: out[b,:] = sigmoid(h_T @ V + Vb); thread t holds h_T[colf]
  float p0 = hf*Vw[2*colf], p1 = hf*Vw[2*colf+1];
  #pragma unroll
  for (int off=32; off>0; off>>=1){
    p0 += __shfl_down(p0, off);
    p1 += __shfl_down(p1, off);
  }
  if ((t & 63) == 0){
    rbuf[(t>>6)*2]   = p0;
    rbuf[(t>>6)*2+1] = p1;
  }
  __syncthreads();
  if (t == 0){
    float s0 = Vb[0], s1 = Vb[1];
    #pragma unroll
    for (int wv=0;wv<8;wv++){ s0 += rbuf[2*wv]; s1 += rbuf[2*wv+1]; }
    out[2*b]   = 1.f/(1.f + __expf(-s0));
    out[2*b+1] = 1.f/(1.f + __expf(-s1));
  }
}

// ---------------------------------------------------------------------------
extern "C" void kernel_launch(void* const* d_in, const int* in_sizes, int n_in,
                              void* d_out, int out_size, void* d_ws, size_t ws_size,
                              hipStream_t stream) {
  const float* x  = (const float*)d_in[0];   // [64,2048,256]
  const float* Ww = (const float*)d_in[1];   // [256,512]
  const float* Wb = (const float*)d_in[2];   // [512]
  const float* Uw = (const float*)d_in[3];   // [512,512]
  const float* Ub = (const float*)d_in[4];   // [512]
  const float* Vw = (const float*)d_in[5];   // [512,2]
  const float* Vb = (const float*)d_in[6];   // [2]
  float* out = (float*)d_out;                // [64,2]

  char* ws = (char*)d_ws;
  _Float16* wxh = (_Float16*)ws;                               // 134,217,728 B
  size_t off = 134217728;
  unsigned* Wp  = (unsigned*)(ws + off); off += 262144;
  uint4*    UrP = (uint4*)   (ws + off); off += (size_t)NRP*512*16;
  uint4*    UtL = (uint4*)   (ws + off);

  prep_pack<<<256, 256, 0, stream>>>(Ww, Uw, Wp, UrP, UtL);
  gemm_wx  <<<4096, 256, 0, stream>>>(x, Wp, Wb, wxh);
  rnn_scan <<<64, 512, 0, stream>>>(UrP, UtL, wxh, Ub, Vw, Vb, out);
}